// Round 1
// baseline (141.138 us; speedup 1.0000x reference)
//
#include <hip/hip_runtime.h>

#define K_RECENT 10

// ---------------------------------------------------------------------------
// Kernel 1: user_pref[b, :] = masked mean of region_emb over last-10 valid
// positions. One block per b, 128 threads (= D).
// ---------------------------------------------------------------------------
__global__ void pref_kernel(const int* __restrict__ user_seq,
                            const int* __restrict__ user_seq_len,
                            const int* __restrict__ poi_region_id,
                            const float* __restrict__ region_emb,
                            float* __restrict__ pref,
                            int S, int D) {
    int b = blockIdx.x;
    int tid = threadIdx.x;
    __shared__ int rids[K_RECENT];

    int len = user_seq_len[b];
    if (tid < K_RECENT) {
        int pos = len - K_RECENT + tid;
        int r = -1;
        if (pos >= 0) {
            int poi = user_seq[b * S + pos];
            r = poi_region_id[poi];
        }
        rids[tid] = r;
    }
    __syncthreads();

    float acc = 0.f;
    int cnt = 0;
#pragma unroll
    for (int j = 0; j < K_RECENT; ++j) {
        int r = rids[j];
        if (r >= 0) {
            ++cnt;
            acc += region_emb[r * D + tid];
        }
    }
    float c = (cnt > 0) ? (float)cnt : 1.f;
    pref[b * D + tid] = acc / c;
}

// ---------------------------------------------------------------------------
// Kernel 2: scores[b, r] = pref[b] . region_emb[r]  (B x R, K = 128)
// Block: 256 threads, covers 8 batch rows (pref tile in LDS, broadcast reads)
// x one 256-wide slab of r. region_emb is 1 MB -> L2-resident.
// ---------------------------------------------------------------------------
__global__ void scores_kernel(const float* __restrict__ pref,
                              const float* __restrict__ region_emb,
                              float* __restrict__ scores,
                              int R) {
    const int BT = 8;          // batch rows per block
    const int D  = 128;
    __shared__ float pl[BT * D];

    int tid = threadIdx.x;
    int b0  = blockIdx.y * BT;

    // 8*128 = 1024 floats = 256 float4, one per thread, coalesced.
    ((float4*)pl)[tid] = ((const float4*)(pref + (size_t)b0 * D))[tid];
    __syncthreads();

    int r = blockIdx.x * blockDim.x + tid;
    if (r >= R) return;

    float acc[BT];
#pragma unroll
    for (int bb = 0; bb < BT; ++bb) acc[bb] = 0.f;

    const float4* erow = (const float4*)(region_emb + (size_t)r * D);
#pragma unroll 8
    for (int d4 = 0; d4 < D / 4; ++d4) {
        float4 e = erow[d4];
#pragma unroll
        for (int bb = 0; bb < BT; ++bb) {
            const float* p = &pl[bb * D + d4 * 4];  // same addr all lanes: LDS broadcast
            acc[bb] += e.x * p[0] + e.y * p[1] + e.z * p[2] + e.w * p[3];
        }
    }
#pragma unroll
    for (int bb = 0; bb < BT; ++bb)
        scores[(size_t)(b0 + bb) * R + r] = acc[bb];
}

// ---------------------------------------------------------------------------
// Kernel 3: out[b, l] = pred[b, l] + alpha * scores[b, poi_region_id[l]]
// The memory-bound bulk: float4 in / float4 out; score row (8 KB) is
// L1-resident per block since blockIdx.y = b.
// ---------------------------------------------------------------------------
__global__ void out_kernel(const float* __restrict__ pred,
                           const float* __restrict__ scores,
                           const int* __restrict__ rid,
                           const float* __restrict__ alpha_p,
                           float* __restrict__ out,
                           int L4, int L, int R) {
    int b = blockIdx.y;
    int i = blockIdx.x * blockDim.x + threadIdx.x;
    if (i >= L4) return;

    float alpha = alpha_p[0];
    int4   r4 = ((const int4*)rid)[i];
    float4 p  = ((const float4*)(pred + (size_t)b * L))[i];
    const float* srow = scores + (size_t)b * R;

    float4 o;
    o.x = fmaf(alpha, srow[r4.x], p.x);
    o.y = fmaf(alpha, srow[r4.y], p.y);
    o.z = fmaf(alpha, srow[r4.z], p.z);
    o.w = fmaf(alpha, srow[r4.w], p.w);
    ((float4*)(out + (size_t)b * L))[i] = o;
}

// Scalar fallback for ragged tails (not expected with L = 50000).
__global__ void out_kernel_scalar(const float* __restrict__ pred,
                                  const float* __restrict__ scores,
                                  const int* __restrict__ rid,
                                  const float* __restrict__ alpha_p,
                                  float* __restrict__ out,
                                  int l0, int L, int R) {
    int b = blockIdx.y;
    int l = l0 + blockIdx.x * blockDim.x + threadIdx.x;
    if (l >= L) return;
    float alpha = alpha_p[0];
    out[(size_t)b * L + l] =
        fmaf(alpha, scores[(size_t)b * R + rid[l]], pred[(size_t)b * L + l]);
}

extern "C" void kernel_launch(void* const* d_in, const int* in_sizes, int n_in,
                              void* d_out, int out_size, void* d_ws, size_t ws_size,
                              hipStream_t stream) {
    const float* pred_base     = (const float*)d_in[0];
    const int*   user_seq      = (const int*)d_in[1];
    const int*   user_seq_len  = (const int*)d_in[2];
    const int*   poi_region_id = (const int*)d_in[3];
    const float* region_emb    = (const float*)d_in[4];
    const float* alpha         = (const float*)d_in[5];
    float*       out           = (float*)d_out;

    const int B = in_sizes[2];              // 1024
    const int S = in_sizes[1] / B;          // 200
    const int L = in_sizes[3];              // 50000
    const int D = 128;
    const int R = in_sizes[4] / D;          // 2000

    // Workspace layout: scores [B*R] f32, pref [B*D] f32  (~8.7 MB total)
    float* scores = (float*)d_ws;
    float* pref   = scores + (size_t)B * R;

    // 1) user_pref
    pref_kernel<<<B, D, 0, stream>>>(user_seq, user_seq_len, poi_region_id,
                                     region_emb, pref, S, D);

    // 2) scores[B,R]
    dim3 g2((R + 255) / 256, B / 8);
    scores_kernel<<<g2, 256, 0, stream>>>(pref, region_emb, scores, R);

    // 3) output
    int L4 = L / 4;
    if (L4 > 0) {
        dim3 g3((L4 + 255) / 256, B);
        out_kernel<<<g3, 256, 0, stream>>>(pred_base, scores, poi_region_id,
                                           alpha, out, L4, L, R);
    }
    int tail = L - L4 * 4;
    if (tail > 0) {
        dim3 gt(1, B);
        out_kernel_scalar<<<gt, 64, 0, stream>>>(pred_base, scores, poi_region_id,
                                                 alpha, out, L4 * 4, L, R);
    }
}

// Round 2
// 117.901 us; speedup vs baseline: 1.1971x; 1.1971x over previous
//
#include <hip/hip_runtime.h>

#define K_RECENT 10

// ---------------------------------------------------------------------------
// Kernel 1: user_pref[b, :] = masked mean of region_emb over last-10 valid
// positions. One block per b, 128 threads (= D).
// ---------------------------------------------------------------------------
__global__ void pref_kernel(const int* __restrict__ user_seq,
                            const int* __restrict__ user_seq_len,
                            const int* __restrict__ poi_region_id,
                            const float* __restrict__ region_emb,
                            float* __restrict__ pref,
                            int S, int D) {
    int b = blockIdx.x;
    int tid = threadIdx.x;
    __shared__ int rids[K_RECENT];

    int len = user_seq_len[b];
    if (tid < K_RECENT) {
        int pos = len - K_RECENT + tid;
        int r = -1;
        if (pos >= 0) {
            int poi = user_seq[b * S + pos];
            r = poi_region_id[poi];
        }
        rids[tid] = r;
    }
    __syncthreads();

    float acc = 0.f;
    int cnt = 0;
#pragma unroll
    for (int j = 0; j < K_RECENT; ++j) {
        int r = rids[j];
        if (r >= 0) {
            ++cnt;
            acc += region_emb[r * D + tid];
        }
    }
    float c = (cnt > 0) ? (float)cnt : 1.f;
    pref[b * D + tid] = acc / c;
}

// ---------------------------------------------------------------------------
// Kernel 2: scores[b, r] = pref[b] . region_emb[r]  (B x R, K = 128)
// Block: 256 threads, covers 8 batch rows (pref tile in LDS, broadcast reads)
// x one 256-wide slab of r. region_emb is 1 MB -> L2-resident.
// ---------------------------------------------------------------------------
__global__ void scores_kernel(const float* __restrict__ pref,
                              const float* __restrict__ region_emb,
                              float* __restrict__ scores,
                              int R) {
    const int BT = 8;          // batch rows per block
    const int D  = 128;
    __shared__ float pl[BT * D];

    int tid = threadIdx.x;
    int b0  = blockIdx.y * BT;

    // 8*128 = 1024 floats = 256 float4, one per thread, coalesced.
    ((float4*)pl)[tid] = ((const float4*)(pref + (size_t)b0 * D))[tid];
    __syncthreads();

    int r = blockIdx.x * blockDim.x + tid;
    if (r >= R) return;

    float acc[BT];
#pragma unroll
    for (int bb = 0; bb < BT; ++bb) acc[bb] = 0.f;

    const float4* erow = (const float4*)(region_emb + (size_t)r * D);
#pragma unroll 8
    for (int d4 = 0; d4 < D / 4; ++d4) {
        float4 e = erow[d4];
#pragma unroll
        for (int bb = 0; bb < BT; ++bb) {
            const float* p = &pl[bb * D + d4 * 4];  // same addr all lanes: LDS broadcast
            acc[bb] += e.x * p[0] + e.y * p[1] + e.z * p[2] + e.w * p[3];
        }
    }
#pragma unroll
    for (int bb = 0; bb < BT; ++bb)
        scores[(size_t)(b0 + bb) * R + r] = acc[bb];
}

// ---------------------------------------------------------------------------
// Kernel 3: out[b, l] = pred[b, l] + alpha * scores[b, poi_region_id[l]]
// Score row (R <= 2048) staged in LDS; gathers hit LDS instead of
// fragmenting into per-cacheline L1 transactions. Each block: one b, one
// chunk of CHUNK_L4 float4 elements (ITERS per thread, stride blockDim).
// ---------------------------------------------------------------------------
#define OUT_BLOCK   256
#define OUT_ITERS   8
#define CHUNK_L4    (OUT_BLOCK * OUT_ITERS)   // 2048 float4 per block
#define MAX_R       2048

__global__ void out_kernel_lds(const float* __restrict__ pred,
                               const float* __restrict__ scores,
                               const int* __restrict__ rid,
                               const float* __restrict__ alpha_p,
                               float* __restrict__ out,
                               int L4, int L, int R) {
    __shared__ float srow[MAX_R];
    int b   = blockIdx.y;
    int tid = threadIdx.x;

    // Cooperative coalesced fill of the score row (R floats, float4-wide).
    const float* g = scores + (size_t)b * R;
    int R4 = R >> 2;
    for (int i = tid; i < R4; i += OUT_BLOCK)
        ((float4*)srow)[i] = ((const float4*)g)[i];
    for (int i = (R4 << 2) + tid; i < R; i += OUT_BLOCK)
        srow[i] = g[i];
    __syncthreads();

    float alpha = alpha_p[0];
    const float4* pp = (const float4*)(pred + (size_t)b * L);
    float4*       op = (float4*)(out + (size_t)b * L);
    const int4*   rp = (const int4*)rid;

    int base = blockIdx.x * CHUNK_L4 + tid;
#pragma unroll
    for (int it = 0; it < OUT_ITERS; ++it) {
        int i = base + it * OUT_BLOCK;
        if (i < L4) {
            int4   r4 = rp[i];
            float4 p  = pp[i];
            float4 o;
            o.x = fmaf(alpha, srow[r4.x], p.x);
            o.y = fmaf(alpha, srow[r4.y], p.y);
            o.z = fmaf(alpha, srow[r4.z], p.z);
            o.w = fmaf(alpha, srow[r4.w], p.w);
            op[i] = o;
        }
    }
}

// Fallback (R > MAX_R, or ragged tail): direct L1 gather.
__global__ void out_kernel_scalar(const float* __restrict__ pred,
                                  const float* __restrict__ scores,
                                  const int* __restrict__ rid,
                                  const float* __restrict__ alpha_p,
                                  float* __restrict__ out,
                                  int l0, int L, int R) {
    int b = blockIdx.y;
    int l = l0 + blockIdx.x * blockDim.x + threadIdx.x;
    if (l >= L) return;
    float alpha = alpha_p[0];
    out[(size_t)b * L + l] =
        fmaf(alpha, scores[(size_t)b * R + rid[l]], pred[(size_t)b * L + l]);
}

extern "C" void kernel_launch(void* const* d_in, const int* in_sizes, int n_in,
                              void* d_out, int out_size, void* d_ws, size_t ws_size,
                              hipStream_t stream) {
    const float* pred_base     = (const float*)d_in[0];
    const int*   user_seq      = (const int*)d_in[1];
    const int*   user_seq_len  = (const int*)d_in[2];
    const int*   poi_region_id = (const int*)d_in[3];
    const float* region_emb    = (const float*)d_in[4];
    const float* alpha         = (const float*)d_in[5];
    float*       out           = (float*)d_out;

    const int B = in_sizes[2];              // 1024
    const int S = in_sizes[1] / B;          // 200
    const int L = in_sizes[3];              // 50000
    const int D = 128;
    const int R = in_sizes[4] / D;          // 2000

    // Workspace layout: scores [B*R] f32, pref [B*D] f32  (~8.7 MB total)
    float* scores = (float*)d_ws;
    float* pref   = scores + (size_t)B * R;

    // 1) user_pref
    pref_kernel<<<B, D, 0, stream>>>(user_seq, user_seq_len, poi_region_id,
                                     region_emb, pref, S, D);

    // 2) scores[B,R]
    dim3 g2((R + 255) / 256, B / 8);
    scores_kernel<<<g2, 256, 0, stream>>>(pref, region_emb, scores, R);

    // 3) output
    int L4 = L / 4;
    if (L4 > 0) {
        if (R <= MAX_R) {
            dim3 g3((L4 + CHUNK_L4 - 1) / CHUNK_L4, B);
            out_kernel_lds<<<g3, OUT_BLOCK, 0, stream>>>(
                pred_base, scores, poi_region_id, alpha, out, L4, L, R);
        } else {
            dim3 g3((L4 + 255) / 256, B);
            // reuse scalar kernel over the vector span
            dim3 gt(((L4 * 4) + 255) / 256, B);
            out_kernel_scalar<<<gt, 256, 0, stream>>>(
                pred_base, scores, poi_region_id, alpha, out, 0, L4 * 4, R);
        }
    }
    int tail = L - L4 * 4;
    if (tail > 0) {
        dim3 gt(1, B);
        out_kernel_scalar<<<gt, 64, 0, stream>>>(pred_base, scores, poi_region_id,
                                                 alpha, out, L4 * 4, L, R);
    }
}

// Round 4
// 96.296 us; speedup vs baseline: 1.4657x; 1.2244x over previous
//
#include <hip/hip_runtime.h>

#define K_RECENT 10

typedef float f32x4 __attribute__((ext_vector_type(4)));
typedef int   i32x4 __attribute__((ext_vector_type(4)));

// ---------------------------------------------------------------------------
// Kernel 1: user_pref[b, :] = masked mean of region_emb over last-10 valid
// positions. One block per b, 128 threads (= D).
// ---------------------------------------------------------------------------
__global__ void pref_kernel(const int* __restrict__ user_seq,
                            const int* __restrict__ user_seq_len,
                            const int* __restrict__ poi_region_id,
                            const float* __restrict__ region_emb,
                            float* __restrict__ pref,
                            int S, int D) {
    int b = blockIdx.x;
    int tid = threadIdx.x;
    __shared__ int rids[K_RECENT];

    int len = user_seq_len[b];
    if (tid < K_RECENT) {
        int pos = len - K_RECENT + tid;
        int r = -1;
        if (pos >= 0) {
            int poi = user_seq[b * S + pos];
            r = poi_region_id[poi];
        }
        rids[tid] = r;
    }
    __syncthreads();

    float acc = 0.f;
    int cnt = 0;
#pragma unroll
    for (int j = 0; j < K_RECENT; ++j) {
        int r = rids[j];
        if (r >= 0) {
            ++cnt;
            acc += region_emb[r * D + tid];
        }
    }
    float c = (cnt > 0) ? (float)cnt : 1.f;
    pref[b * D + tid] = acc / c;
}

// ---------------------------------------------------------------------------
// Kernel 2: scores[b, r] = pref[b] . region_emb[r]  (B x R, K = 128)
// Block: 256 threads, 8 batch rows (pref tile in LDS, float4 broadcast reads
// -> ds_read_b128, conflict-free) x one 256-wide slab of r.
// ---------------------------------------------------------------------------
__global__ void scores_kernel(const float* __restrict__ pref,
                              const float* __restrict__ region_emb,
                              float* __restrict__ scores,
                              int R) {
    const int BT = 8;          // batch rows per block
    const int D  = 128;
    __shared__ float pl[BT * D];

    int tid = threadIdx.x;
    int b0  = blockIdx.y * BT;

    // 8*128 = 1024 floats = 256 float4, one per thread, coalesced.
    ((f32x4*)pl)[tid] = ((const f32x4*)(pref + (size_t)b0 * D))[tid];
    __syncthreads();

    int r = blockIdx.x * blockDim.x + tid;
    if (r >= R) return;

    float acc[BT];
#pragma unroll
    for (int bb = 0; bb < BT; ++bb) acc[bb] = 0.f;

    const f32x4* erow = (const f32x4*)(region_emb + (size_t)r * D);
#pragma unroll 8
    for (int d4 = 0; d4 < D / 4; ++d4) {
        f32x4 e = erow[d4];
#pragma unroll
        for (int bb = 0; bb < BT; ++bb) {
            // block-uniform 16B-aligned LDS read -> ds_read_b128 broadcast
            f32x4 pv = *reinterpret_cast<const f32x4*>(&pl[bb * D + d4 * 4]);
            acc[bb] = fmaf(e.x, pv.x,
                      fmaf(e.y, pv.y,
                      fmaf(e.z, pv.z,
                      fmaf(e.w, pv.w, acc[bb]))));
        }
    }
#pragma unroll
    for (int bb = 0; bb < BT; ++bb)
        scores[(size_t)(b0 + bb) * R + r] = acc[bb];
}

// ---------------------------------------------------------------------------
// Kernel 3: out[b, l] = pred[b, l] + alpha * scores[b, poi_region_id[l]]
// Score row staged in LDS. F chunks per row; deep unrolled unchecked main
// loop for MLP (many loads in flight), masked tail, nontemporal out stores.
// ---------------------------------------------------------------------------
#define OUT_BLOCK   256
#define OUT_F       4
#define MAX_R       2048

__global__ void out_kernel_lds(const float* __restrict__ pred,
                               const float* __restrict__ scores,
                               const int* __restrict__ rid,
                               const float* __restrict__ alpha_p,
                               float* __restrict__ out,
                               int L4, int L, int R, int CPB) {
    __shared__ float srow[MAX_R];
    int b   = blockIdx.y;
    int tid = threadIdx.x;
    float alpha = alpha_p[0];

    // Cooperative coalesced fill of the score row (R floats, float4-wide).
    const float* g = scores + (size_t)b * R;
    int R4 = R >> 2;
    for (int i = tid; i < R4; i += OUT_BLOCK)
        ((f32x4*)srow)[i] = ((const f32x4*)g)[i];
    for (int i = (R4 << 2) + tid; i < R; i += OUT_BLOCK)
        srow[i] = g[i];
    __syncthreads();

    int base = blockIdx.x * CPB;
    int n = min(CPB, L4 - base);
    if (n <= 0) return;

    const i32x4* rp = (const i32x4*)rid + base;
    const f32x4* pp = (const f32x4*)(pred + (size_t)b * L) + base;
    f32x4*       op = (f32x4*)(out + (size_t)b * L) + base;

    int full = n >> 8;                    // full (unchecked) 256-wide rounds
#pragma unroll 4
    for (int k = 0; k < full; ++k) {
        int i = k * OUT_BLOCK + tid;
        i32x4 r4 = rp[i];
        f32x4 p  = pp[i];
        f32x4 o;
        o.x = fmaf(alpha, srow[r4.x], p.x);
        o.y = fmaf(alpha, srow[r4.y], p.y);
        o.z = fmaf(alpha, srow[r4.z], p.z);
        o.w = fmaf(alpha, srow[r4.w], p.w);
        __builtin_nontemporal_store(o, &op[i]);
    }
    int i = full * OUT_BLOCK + tid;
    if (i < n) {
        i32x4 r4 = rp[i];
        f32x4 p  = pp[i];
        f32x4 o;
        o.x = fmaf(alpha, srow[r4.x], p.x);
        o.y = fmaf(alpha, srow[r4.y], p.y);
        o.z = fmaf(alpha, srow[r4.z], p.z);
        o.w = fmaf(alpha, srow[r4.w], p.w);
        __builtin_nontemporal_store(o, &op[i]);
    }
}

// Fallback (R > MAX_R, or ragged tail): direct L1 gather.
__global__ void out_kernel_scalar(const float* __restrict__ pred,
                                  const float* __restrict__ scores,
                                  const int* __restrict__ rid,
                                  const float* __restrict__ alpha_p,
                                  float* __restrict__ out,
                                  int l0, int L, int R) {
    int b = blockIdx.y;
    int l = l0 + blockIdx.x * blockDim.x + threadIdx.x;
    if (l >= L) return;
    float alpha = alpha_p[0];
    out[(size_t)b * L + l] =
        fmaf(alpha, scores[(size_t)b * R + rid[l]], pred[(size_t)b * L + l]);
}

extern "C" void kernel_launch(void* const* d_in, const int* in_sizes, int n_in,
                              void* d_out, int out_size, void* d_ws, size_t ws_size,
                              hipStream_t stream) {
    const float* pred_base     = (const float*)d_in[0];
    const int*   user_seq      = (const int*)d_in[1];
    const int*   user_seq_len  = (const int*)d_in[2];
    const int*   poi_region_id = (const int*)d_in[3];
    const float* region_emb    = (const float*)d_in[4];
    const float* alpha         = (const float*)d_in[5];
    float*       out           = (float*)d_out;

    const int B = in_sizes[2];              // 1024
    const int S = in_sizes[1] / B;          // 200
    const int L = in_sizes[3];              // 50000
    const int D = 128;
    const int R = in_sizes[4] / D;          // 2000

    // Workspace layout: scores [B*R] f32, pref [B*D] f32  (~8.7 MB total)
    float* scores = (float*)d_ws;
    float* pref   = scores + (size_t)B * R;

    // 1) user_pref
    pref_kernel<<<B, D, 0, stream>>>(user_seq, user_seq_len, poi_region_id,
                                     region_emb, pref, S, D);

    // 2) scores[B,R]
    dim3 g2((R + 255) / 256, B / 8);
    scores_kernel<<<g2, 256, 0, stream>>>(pref, region_emb, scores, R);

    // 3) output
    int L4 = L / 4;
    if (L4 > 0) {
        if (R <= MAX_R) {
            int CPB = (L4 + OUT_F - 1) / OUT_F;
            dim3 g3(OUT_F, B);
            out_kernel_lds<<<g3, OUT_BLOCK, 0, stream>>>(
                pred_base, scores, poi_region_id, alpha, out, L4, L, R, CPB);
        } else {
            dim3 gt(((L4 * 4) + 255) / 256, B);
            out_kernel_scalar<<<gt, 256, 0, stream>>>(
                pred_base, scores, poi_region_id, alpha, out, 0, L4 * 4, R);
        }
    }
    int tail = L - L4 * 4;
    if (tail > 0) {
        dim3 gt(1, B);
        out_kernel_scalar<<<gt, 64, 0, stream>>>(pred_base, scores, poi_region_id,
                                                 alpha, out, L4 * 4, L, R);
    }
}